// Round 11
// baseline (120.178 us; speedup 1.0000x reference)
//
#include <hip/hip_runtime.h>
#include <hip/hip_bf16.h>
#include <stdint.h>

// BigBird block-sparse attention, MI355X bf16-MFMA implementation.
// B=2 S=4096 H=768 NH=12 D=64 BLK=64 NB=64 R=3
#define NHD 12
#define SLEN 4096
#define DH 64
#define NBLK 64
#define HDIM 768
#define PEN -10000.0f
#define LOG2E 1.44269504f

typedef __bf16 bf16x8 __attribute__((ext_vector_type(8)));
typedef float f32x4 __attribute__((ext_vector_type(4)));
typedef unsigned short u16x8 __attribute__((ext_vector_type(8)));

__device__ __forceinline__ unsigned short f2bf(float x) {
    union { float f; unsigned u; } v; v.f = x;
    unsigned r = v.u + 0x7fffu + ((v.u >> 16) & 1u);   // RNE
    return (unsigned short)(r >> 16);
}

// async global->LDS, 16B per lane, LDS dest = wave-uniform base + lane*16
__device__ __forceinline__ void gl2lds16(const void* g, void* l) {
    __builtin_amdgcn_global_load_lds(
        (const __attribute__((address_space(1))) void*)g,
        (__attribute__((address_space(3))) void*)l, 16, 0, 0);
}

// ---------------- cast hidden_states f32 -> bf16 ----------------
__global__ void k_cast_hs(const float* __restrict__ in, unsigned short* __restrict__ out, int n8) {
    int i = blockIdx.x * blockDim.x + threadIdx.x;
    if (i >= n8) return;
    const float4* p = (const float4*)in + (size_t)i * 2;
    float4 a = p[0], b = p[1];
    u16x8 o;
    o[0]=f2bf(a.x); o[1]=f2bf(a.y); o[2]=f2bf(a.z); o[3]=f2bf(a.w);
    o[4]=f2bf(b.x); o[5]=f2bf(b.y); o[6]=f2bf(b.z); o[7]=f2bf(b.w);
    ((u16x8*)out)[i] = o;
}

// ---------------- W (k,n) f32 -> Wt (n,k) bf16 ----------------
__global__ void k_wt(const float* __restrict__ Wq, const float* __restrict__ Wk,
                     const float* __restrict__ Wv, unsigned short* __restrict__ wt) {
    const float* W = blockIdx.z == 0 ? Wq : (blockIdx.z == 1 ? Wk : Wv);
    unsigned short* out = wt + (size_t)blockIdx.z * HDIM * HDIM;
    __shared__ float tile[64][65];
    int t = threadIdx.x;
    int k0 = blockIdx.x * 64, n0 = blockIdx.y * 64;
    int r = t >> 2, c4 = t & 3;
#pragma unroll
    for (int j = 0; j < 16; j += 4) {
        float4 v = *(const float4*)&W[(size_t)(k0 + r) * HDIM + n0 + c4 * 16 + j];
        tile[r][c4*16+j+0] = v.x; tile[r][c4*16+j+1] = v.y;
        tile[r][c4*16+j+2] = v.z; tile[r][c4*16+j+3] = v.w;
    }
    __syncthreads();
    u16x8 o0, o1;
#pragma unroll
    for (int j = 0; j < 8; ++j) o0[j] = f2bf(tile[c4*16 + j][r]);
#pragma unroll
    for (int j = 0; j < 8; ++j) o1[j] = f2bf(tile[c4*16 + 8 + j][r]);
    *(u16x8*)&out[(size_t)(n0 + r) * HDIM + k0 + c4*16]     = o0;
    *(u16x8*)&out[(size_t)(n0 + r) * HDIM + k0 + c4*16 + 8] = o1;
}

// ---------------- projection GEMM (m97 structure, template-specialized) ----------------
template<bool TR>
__global__ __launch_bounds__(256) void k_proj(const unsigned short* __restrict__ hsb,
                                              const unsigned short* __restrict__ wtb,
                                              unsigned short* __restrict__ outbuf) {
    __shared__ __align__(16) unsigned short As[8192];   // [128 rows][128B], swizzled slots
    __shared__ __align__(16) unsigned short Bs[8192];
    const char* Abase = (const char*)hsb;
    const char* Bbase = (const char*)(wtb + (size_t)blockIdx.z * HDIM * HDIM);
    unsigned short* out = outbuf + (size_t)blockIdx.z * (2u * NHD * SLEN * DH);
    int m0 = blockIdx.x * 128, n0 = blockIdx.y * 128;
    int t = threadIdx.x;
    int w = t >> 6, l = t & 63, g = l >> 4, c = l & 15;
    int wm = w >> 1, wn = w & 1;
    int lr = l >> 3, ls = l & 7, sw = ls ^ lr;          // stage swizzle (slot ^= row&7)
    int c7 = c & 7;
    f32x4 acc[4][4];
#pragma unroll
    for (int i = 0; i < 4; ++i)
#pragma unroll
        for (int j = 0; j < 4; ++j) acc[i][j] = (f32x4){0.f,0.f,0.f,0.f};

    for (int kt = 0; kt < HDIM; kt += 64) {
        __syncthreads();
#pragma unroll
        for (int i = 0; i < 4; ++i) {
            int rowb = w * 32 + i * 8;                   // 8 rows per issue
            gl2lds16(Abase + (size_t)(m0 + rowb + lr) * 1536 + kt * 2 + sw * 16,
                     (char*)As + rowb * 128);
            gl2lds16(Bbase + (size_t)(n0 + rowb + lr) * 1536 + kt * 2 + sw * 16,
                     (char*)Bs + rowb * 128);
        }
        __syncthreads();                                 // drains vmcnt before reads
#pragma unroll
        for (int ks = 0; ks < 2; ++ks) {
            bf16x8 af[4], bf_[4];
#pragma unroll
            for (int mt = 0; mt < 4; ++mt)
                af[mt]  = *(const bf16x8*)((const char*)As
                            + (64*wm + 16*mt + c) * 128 + (((ks*4 + g) ^ c7) * 16));
#pragma unroll
            for (int nt = 0; nt < 4; ++nt)
                bf_[nt] = *(const bf16x8*)((const char*)Bs
                            + (64*wn + 16*nt + c) * 128 + (((ks*4 + g) ^ c7) * 16));
#pragma unroll
            for (int i = 0; i < 4; ++i)
#pragma unroll
                for (int j = 0; j < 4; ++j)
                    acc[i][j] = TR
                        ? __builtin_amdgcn_mfma_f32_16x16x32_bf16(bf_[i], af[j], acc[i][j], 0, 0, 0)
                        : __builtin_amdgcn_mfma_f32_16x16x32_bf16(af[i], bf_[j], acc[i][j], 0, 0, 0);
        }
    }
#pragma unroll
    for (int i = 0; i < 4; ++i)
#pragma unroll
        for (int j = 0; j < 4; ++j)
#pragma unroll
            for (int r2 = 0; r2 < 4; ++r2) {
                if (!TR) {
                    int m = m0 + 64*wm + 16*i + 4*g + r2;     // s-dim (acc row)
                    int n = n0 + 64*wn + 16*j + c;            // h*64+d (acc col)
                    int bb = m >> 12, s = m & 4095;
                    int hh = n >> 6,  d = n & 63;
                    out[(((size_t)bb * NHD + hh) * SLEN + s) * DH + d] = f2bf(acc[i][j][r2]);
                } else {
                    int n = n0 + 64*wn + 16*i + 4*g + r2;     // h*64+d (acc row)
                    int m = m0 + 64*wm + 16*j + c;            // s-dim (acc col)
                    int bb = m >> 12, s = m & 4095;
                    int hh = n >> 6,  d = n & 63;
                    out[(((size_t)bb * NHD + hh) * DH + d) * SLEN + s] = f2bf(acc[i][j][r2]);
                }
            }
}

// ---------------- flash-style block-sparse attention (v9) ----------------
// KVBLK=128: 2 key-blocks per step, 4 steps, ONE barrier per step (5 total
// vs v8's 17). K,V both double-buffered (32+32KB) + P 16KB = 80KB -> 2
// blocks/CU (= v8's measured effective residency, so no occupancy loss).
// stage(t+1) issued at step start, drained by the end-of-step barrier ->
// a full ~2x-longer compute phase covers the load latency (v8 drained
// loads issued only ~300-600 cycles earlier, twice per 64-key step).
__global__ __launch_bounds__(256) void k_attn(
    const unsigned short* __restrict__ Qb, const unsigned short* __restrict__ Kb,
    const unsigned short* __restrict__ VTb,
    const int* __restrict__ rand_attn,
    const float* __restrict__ band_mask, const float* __restrict__ from_mask,
    const float* __restrict__ to_mask, const float* __restrict__ fbm,
    const float* __restrict__ tbm,
    float* __restrict__ out, float* __restrict__ partials)
{
    __shared__ __align__(16) unsigned short Kt[2][8192];   // [buf][128 keys x 64 d] 32KB
    __shared__ __align__(16) unsigned short Vt[2][8192];   // [buf][64 d x 128 keys] 32KB
    __shared__ __align__(16) char plds[4 * 4096];          // per-wave P (16q x 128k) 16KB

    const float SC = 0.125f * LOG2E;          // qk scale in log2 domain
    const float PL = PEN * LOG2E;             // penalty in log2 domain
    const float THR2 = 8.0f * LOG2E;          // defer-max threshold (log2)

    int i0 = blockIdx.x;
    int gid = (i0 & 7) * 234 + (i0 >> 3);           // XCD swizzle (1872 = 8*234)
    int bh = gid / 78, task = gid - bh * 78;
    int b = bh / NHD, h = bh - b * NHD;
    int t = threadIdx.x;
    int wq = t >> 6, l = t & 63, g = l >> 4, c = l & 15;
    int lr = l >> 3, ls = l & 7, sw = ls ^ lr;      // K stage swizzle
    int c7 = c & 7;

    // ---- task -> 8 slot descriptors (kv: 0=to_mask 1=band 2=rand 3=skip) ----
    int row, mode = 0, pslot = 0;
    int blkj[8], kvj[8], sbj[8];
#pragma unroll
    for (int j = 0; j < 8; ++j) sbj[j] = 0;
    if (task < 8) {
        row = 0; mode = 1; pslot = task;
#pragma unroll
        for (int j = 0; j < 8; ++j) { blkj[j] = task * 8 + j; kvj[j] = 0; }
    } else if (task >= 70) {
        row = 63; mode = 1; pslot = task - 70;
#pragma unroll
        for (int j = 0; j < 8; ++j) { blkj[j] = pslot * 8 + j; kvj[j] = 0; }
    } else {
        row = task - 7;                              // 1..62
        int rbase = ((b * NHD + h) * 62 + (row - 1)) * 3;
        blkj[4] = rand_attn[rbase];
        blkj[5] = rand_attn[rbase + 1];
        blkj[6] = rand_attn[rbase + 2];
        kvj[4] = kvj[5] = kvj[6] = 2;
        blkj[0] = 0; kvj[0] = 0;
        if (row == 1) {
            blkj[1]=1;  blkj[2]=2;  blkj[3]=63; kvj[1]=kvj[2]=kvj[3]=0;
            blkj[7]=0;  kvj[7]=3;
        } else if (row == 62) {
            blkj[1]=61; blkj[2]=62; blkj[3]=63; kvj[1]=kvj[2]=kvj[3]=0;
            blkj[7]=0;  kvj[7]=3;
        } else {
            blkj[1]=row-1; blkj[2]=row; blkj[3]=row+1;
            kvj[1]=kvj[2]=kvj[3]=1; sbj[1]=0; sbj[2]=64; sbj[3]=128;
            blkj[7]=63; kvj[7]=0;
        }
    }

    size_t bhoff = (size_t)bh * SLEN * DH;
    const char* Kbase = (const char*)(Kb + bhoff);                  // [key][128B]
    const char* Vbase = (const char*)(VTb + (size_t)bh * DH * SLEN); // [d][8192B]
    int q0 = row * 64 + wq * 16;

    // Q fragments (held in registers whole kernel)
    bf16x8 qf[2];
#pragma unroll
    for (int kk = 0; kk < 2; ++kk)
        qf[kk] = *(const bf16x8*)&Qb[bhoff + (size_t)(q0 + c) * DH + kk * 32 + 8 * g];

    float fmq = fbm[(b * NBLK + row) * 64 + wq * 16 + c];
    size_t bm_base = ((size_t)(b * 60 + row - 2) * 64 + (wq * 16 + c)) * 192;
    int tm_base = b * SLEN;

    float m_run = -1e30f, l_run = 0.f;
    f32x4 o_acc[4];
#pragma unroll
    for (int dt = 0; dt < 4; ++dt) o_acc[dt] = (f32x4){0.f,0.f,0.f,0.f};

    char* myl = plds + wq * 4096 + c * 256;       // 16q x 256B rows
    int swz = c7 << 4;

    // ---- stage 128-key tile (blkA keys 0..63, blkB keys 64..127) ----
    auto stage = [&](int blkA, int blkB, int nb) __attribute__((always_inline)) {
#pragma unroll
        for (int ii = 0; ii < 4; ++ii) {
            int ch = wq * 4 + ii;                          // 0..15
            {   // K: rows = key (128 x 128B); chunk = 8 key rows
                int blk = (ch >> 3) ? blkB : blkA;
                int keyrow = (ch & 7) * 8 + lr;
                gl2lds16(Kbase + (size_t)blk * 8192 + (size_t)keyrow * 128 + sw * 16,
                         (char*)&Kt[nb][0] + ch * 1024);
            }
            {   // V: rows = d (64 x 256B); chunk = 4 d rows; swizzle slot^=(row&7)
                int drow = ch * 4 + (l >> 4);
                int sl = (l & 15) ^ ((4 * (ch & 1) + (l >> 4)) & 7);
                int blk = (sl & 8) ? blkB : blkA;
                gl2lds16(Vbase + (size_t)drow * 8192 + (size_t)blk * 128 + (sl & 7) * 16,
                         (char*)&Vt[nb][0] + ch * 1024);
            }
        }
    };

    // ---- mask -> precomputed penalty (log2 domain) ----
    auto loadpen = [&](int kv, int blk, int sb, float4* pen) __attribute__((always_inline)) {
        if (kv == 0) {
#pragma unroll
            for (int mt = 0; mt < 4; ++mt) {
                float4 mk = *(const float4*)&to_mask[tm_base + blk * 64 + mt * 16 + 4 * g];
                pen[mt].x = (1.f - mk.x) * PL; pen[mt].y = (1.f - mk.y) * PL;
                pen[mt].z = (1.f - mk.z) * PL; pen[mt].w = (1.f - mk.w) * PL;
            }
        } else if (kv == 1) {
#pragma unroll
            for (int mt = 0; mt < 4; ++mt) {
                float4 mk = *(const float4*)&band_mask[bm_base + sb + mt * 16 + 4 * g];
                pen[mt].x = (1.f - mk.x) * PL; pen[mt].y = (1.f - mk.y) * PL;
                pen[mt].z = (1.f - mk.z) * PL; pen[mt].w = (1.f - mk.w) * PL;
            }
        } else if (kv == 2) {
#pragma unroll
            for (int mt = 0; mt < 4; ++mt) {
                float4 tb = *(const float4*)&tbm[(size_t)(b * NBLK + blk) * 64 + mt * 16 + 4 * g];
                pen[mt].x = (1.f - fmq * tb.x) * PL; pen[mt].y = (1.f - fmq * tb.y) * PL;
                pen[mt].z = (1.f - fmq * tb.z) * PL; pen[mt].w = (1.f - fmq * tb.w) * PL;
            }
        }
    };

    // ---- one 128-key step: QK^T both slots + softmax + pack + PV ----
    auto step128 = [&](int nb, bool actB, const float4* pen0, const float4* pen1)
        __attribute__((always_inline)) {
        const char* Kl = (const char*)&Kt[nb][0];
        // slot 0 scores
        f32x4 sa0[4], sa1[4];
#pragma unroll
        for (int mt = 0; mt < 4; ++mt) {
            bf16x8 k0 = *(const bf16x8*)(Kl + (16*mt + c) * 128 + ((g ^ c7) * 16));
            bf16x8 k1 = *(const bf16x8*)(Kl + (16*mt + c) * 128 + (((4 + g) ^ c7) * 16));
            f32x4 s = __builtin_amdgcn_mfma_f32_16x16x32_bf16(k0, qf[0], (f32x4){0,0,0,0}, 0, 0, 0);
            sa0[mt] = __builtin_amdgcn_mfma_f32_16x16x32_bf16(k1, qf[1], s, 0, 0, 0);
        }
        if (actB) {
#pragma unroll
            for (int mt = 0; mt < 4; ++mt) {
                bf16x8 k0 = *(const bf16x8*)(Kl + (64 + 16*mt + c) * 128 + ((g ^ c7) * 16));
                bf16x8 k1 = *(const bf16x8*)(Kl + (64 + 16*mt + c) * 128 + (((4 + g) ^ c7) * 16));
                f32x4 s = __builtin_amdgcn_mfma_f32_16x16x32_bf16(k0, qf[0], (f32x4){0,0,0,0}, 0, 0, 0);
                sa1[mt] = __builtin_amdgcn_mfma_f32_16x16x32_bf16(k1, qf[1], s, 0, 0, 0);
            }
        }
        // scale + penalty
#pragma unroll
        for (int mt = 0; mt < 4; ++mt) {
            sa0[mt][0] = sa0[mt][0] * SC + pen0[mt].x;
            sa0[mt][1] = sa0[mt][1] * SC + pen0[mt].y;
            sa0[mt][2] = sa0[mt][2] * SC + pen0[mt].z;
            sa0[mt][3] = sa0[mt][3] * SC + pen0[mt].w;
        }
        if (actB) {
#pragma unroll
            for (int mt = 0; mt < 4; ++mt) {
                sa1[mt][0] = sa1[mt][0] * SC + pen1[mt].x;
                sa1[mt][1] = sa1[mt][1] * SC + pen1[mt].y;
                sa1[mt][2] = sa1[mt][2] * SC + pen1[mt].z;
                sa1[mt][3] = sa1[mt][3] * SC + pen1[mt].w;
            }
        }
        // online softmax over 128 (or 64) keys
        float pm = -1e30f;
#pragma unroll
        for (int mt = 0; mt < 4; ++mt)
#pragma unroll
            for (int r2 = 0; r2 < 4; ++r2) pm = fmaxf(pm, sa0[mt][r2]);
        if (actB) {
#pragma unroll
            for (int mt = 0; mt < 4; ++mt)
#pragma unroll
                for (int r2 = 0; r2 < 4; ++r2) pm = fmaxf(pm, sa1[mt][r2]);
        }
        pm = fmaxf(pm, __shfl_xor(pm, 16));
        pm = fmaxf(pm, __shfl_xor(pm, 32));
        if (__ballot(pm > m_run + THR2)) {
            bool need = pm > m_run + THR2;
            float mnew = need ? pm : m_run;
            float scale = exp2f(m_run - mnew);
            m_run = mnew;
            l_run *= scale;
#pragma unroll
            for (int dt = 0; dt < 4; ++dt)
#pragma unroll
                for (int r2 = 0; r2 < 4; ++r2) o_acc[dt][r2] *= scale;
        }
        float rs = 0.f;
#pragma unroll
        for (int mt = 0; mt < 4; ++mt)
#pragma unroll
            for (int r2 = 0; r2 < 4; ++r2) {
                float e = exp2f(sa0[mt][r2] - m_run);
                sa0[mt][r2] = e; rs += e;
            }
        if (actB) {
#pragma unroll
            for (int mt = 0; mt < 4; ++mt)
#pragma unroll
                for (int r2 = 0; r2 < 4; ++r2) {
                    float e = exp2f(sa1[mt][r2] - m_run);
                    sa1[mt][r2] = e; rs += e;
                }
        }
        rs += __shfl_xor(rs, 16);
        rs += __shfl_xor(rs, 32);
        l_run += rs;
        // pack P -> wave-private LDS (rows 256B, XOR swizzle bits 4-6)
#pragma unroll
        for (int mt = 0; mt < 4; ++mt) {
            union { __bf16 hh[4]; unsigned long long u; } pk_;
            pk_.hh[0] = (__bf16)sa0[mt][0]; pk_.hh[1] = (__bf16)sa0[mt][1];
            pk_.hh[2] = (__bf16)sa0[mt][2]; pk_.hh[3] = (__bf16)sa0[mt][3];
            *(unsigned long long*)(myl + ((mt * 32 + g * 8) ^ swz)) = pk_.u;
        }
        if (actB) {
#pragma unroll
            for (int mt = 0; mt < 4; ++mt) {
                union { __bf16 hh[4]; unsigned long long u; } pk_;
                pk_.hh[0] = (__bf16)sa1[mt][0]; pk_.hh[1] = (__bf16)sa1[mt][1];
                pk_.hh[2] = (__bf16)sa1[mt][2]; pk_.hh[3] = (__bf16)sa1[mt][3];
                *(unsigned long long*)(myl + ((128 + mt * 32 + g * 8) ^ swz)) = pk_.u;
            }
        } else {
#pragma unroll
            for (int mt = 0; mt < 4; ++mt)
                *(unsigned long long*)(myl + ((128 + mt * 32 + g * 8) ^ swz)) = 0ULL;
        }
        asm volatile("" ::: "memory");     // same-wave DS: writes before reads
        // PV: O^T += V^T * P over 128 keys
        bf16x8 pa[4];
#pragma unroll
        for (int kk = 0; kk < 4; ++kk)
            pa[kk] = *(const bf16x8*)(myl + ((kk * 64 + g * 16) ^ swz));
        const char* Vl = (const char*)&Vt[nb][0];
#pragma unroll
        for (int dt = 0; dt < 4; ++dt) {
#pragma unroll
            for (int kk = 0; kk < 4; ++kk) {
                bf16x8 v = *(const bf16x8*)(Vl + (dt*16 + c) * 256 + ((kk*64 + 16*g) ^ swz));
                o_acc[dt] = __builtin_amdgcn_mfma_f32_16x16x32_bf16(v, pa[kk], o_acc[dt], 0, 0, 0);
            }
        }
    };

    // ---- 4-step loop, one barrier per step ----
    float4 pen0[4], pen1[4];
    stage(blkj[0], blkj[1], 0);
    __syncthreads();                                  // drains tile 0
#pragma unroll
    for (int tt = 0; tt < 4; ++tt) {
        int nb = tt & 1;
        if (tt < 3) stage(blkj[2*tt + 2], blkj[2*tt + 3], nb ^ 1);
        bool actB = (kvj[2*tt + 1] != 3);             // block-uniform
        loadpen(kvj[2*tt], blkj[2*tt], sbj[2*tt], pen0);
        if (actB) loadpen(kvj[2*tt + 1], blkj[2*tt + 1], sbj[2*tt + 1], pen1);
        step128(nb, actB, pen0, pen1);
        __syncthreads();                              // all waves done with buf; tile t+1 landed
    }

    if (mode == 0) {
        int s = q0 + c;
        float fm = from_mask[b * SLEN + s];
        float inv = fm / l_run;
        size_t obase = ((size_t)b * SLEN + s) * HDIM + h * DH;
#pragma unroll
        for (int dt = 0; dt < 4; ++dt) {
            float4 val;
            val.x = o_acc[dt][0] * inv;
            val.y = o_acc[dt][1] * inv;
            val.z = o_acc[dt][2] * inv;
            val.w = o_acc[dt][3] * inv;
            *(float4*)&out[obase + dt * 16 + 4 * g] = val;
        }
    } else {
        float* pb = partials + (size_t)((bh * 2 + (row == 63 ? 1 : 0)) * 8 + pslot) * 4224;
        int q = wq * 16 + c;
#pragma unroll
        for (int dt = 0; dt < 4; ++dt) {
            float4 val;
            val.x = o_acc[dt][0]; val.y = o_acc[dt][1];
            val.z = o_acc[dt][2]; val.w = o_acc[dt][3];
            *(float4*)&pb[q * 64 + dt * 16 + 4 * g] = val;
        }
        if (g == 0) {
            pb[4096 + q] = m_run;                     // log2 domain
            pb[4160 + q] = l_run;
        }
    }
}

// ---------------- combine 8 partials for row-blocks 0 and 63 ----------------
// partial o_i is raw (unnormalized); m_i in log2 domain -> weight exp2(m_i-M).
__global__ void k_combine(const float* __restrict__ partials, const float* __restrict__ from_mask,
                          float* __restrict__ out) {
    int gid = blockIdx.x;          // 48 = bh*2 + rb
    int bh = gid >> 1, rb = gid & 1;
    int b = bh / NHD, h = bh - b * NHD;
    int t = threadIdx.x;           // 256
    int q = t >> 2, dc = (t & 3) * 16;
    const float* base = partials + (size_t)gid * 8 * 4224;
    float M = -1e30f;
#pragma unroll
    for (int i = 0; i < 8; ++i) M = fmaxf(M, base[i*4224 + 4096 + q]);
    float L = 0.f, cx[16];
#pragma unroll
    for (int j = 0; j < 16; ++j) cx[j] = 0.f;
    for (int i = 0; i < 8; ++i) {
        float w = exp2f(base[i*4224 + 4096 + q] - M);
        L += base[i*4224 + 4160 + q] * w;
#pragma unroll
        for (int j = 0; j < 16; ++j) cx[j] += base[i*4224 + q*64 + dc + j] * w;
    }
    int s = (rb ? 4032 : 0) + q;
    float fm = from_mask[b * SLEN + s];
    float inv = fm / L;
#pragma unroll
    for (int j = 0; j < 16; ++j)
        out[((size_t)b * SLEN + s) * HDIM + h * DH + dc + j] = cx[j] * inv;
}

extern "C" void kernel_launch(void* const* d_in, const int* in_sizes, int n_in,
                              void* d_out, int out_size, void* d_ws, size_t ws_size,
                              hipStream_t stream) {
    const float* hs    = (const float*)d_in[0];
    const float* Wq    = (const float*)d_in[1];
    const float* Wk    = (const float*)d_in[2];
    const float* Wv    = (const float*)d_in[3];
    const float* band  = (const float*)d_in[4];
    const float* fromm = (const float*)d_in[5];
    const float* tom   = (const float*)d_in[6];
    const float* fbm   = (const float*)d_in[7];
    const float* tbm   = (const float*)d_in[8];
    const int*   ra    = (const int*)d_in[9];      // harness passes integers as int32
    float* out = (float*)d_out;

    // workspace layout (bytes):
    //  [0, 12.58M)  hsb  (bf16 hidden)
    //  [12.58M, 16.12M) wtb (3x768x768 bf16)
    //  [16.12M, 53.87M) qkv: z=0 Q (bh,s,d), z=1 K (bh,s,d), z=2 V^T (bh,d,s)
    //  [53.87M, 60.36M) partials (48 x 8 x 4224 f32)
    char* ws = (char*)d_ws;
    unsigned short* hsb = (unsigned short*)(ws);
    unsigned short* wtb = (unsigned short*)(ws + 12582912);
    unsigned short* qkv = (unsigned short*)(ws + 16121856);
    float* partials     = (float*)(ws + 53870592);

    k_cast_hs<<<3072, 256, 0, stream>>>(hs, hsb, 786432);
    k_wt<<<dim3(12, 12, 3), 256, 0, stream>>>(Wq, Wk, Wv, wtb);
    k_proj<false><<<dim3(64, 6, 2), 256, 0, stream>>>(hsb, wtb, qkv);
    k_proj<true><<<dim3(64, 6, 1), 256, 0, stream>>>(hsb, wtb + 2 * HDIM * HDIM,
                                                     qkv + 2 * 6291456);
    k_attn<<<1872, 256, 0, stream>>>(qkv, qkv + 6291456, qkv + 2 * 6291456, ra,
                                     band, fromm, tom, fbm, tbm, out, partials);
    k_combine<<<48, 256, 0, stream>>>(partials, fromm, out);
}

// Round 15
// 110.165 us; speedup vs baseline: 1.0909x; 1.0909x over previous
//
#include <hip/hip_runtime.h>
#include <hip/hip_bf16.h>
#include <stdint.h>

// BigBird block-sparse attention, MI355X bf16-MFMA implementation.
// B=2 S=4096 H=768 NH=12 D=64 BLK=64 NB=64 R=3
// Round-15: verbatim revert to the round-10 known-good kernel (110.3 us).
// Counted-vmcnt/raw-barrier experiments (r12-r14) failed correctness 3x
// (intermittent LDS races not fixable at HIP source level without the
// exact m201 template) -- closed. __syncthreads-based sync throughout.
#define NHD 12
#define SLEN 4096
#define DH 64
#define NBLK 64
#define HDIM 768
#define PEN -10000.0f
#define LOG2E 1.44269504f

typedef __bf16 bf16x8 __attribute__((ext_vector_type(8)));
typedef float f32x4 __attribute__((ext_vector_type(4)));
typedef unsigned short u16x8 __attribute__((ext_vector_type(8)));

__device__ __forceinline__ unsigned short f2bf(float x) {
    union { float f; unsigned u; } v; v.f = x;
    unsigned r = v.u + 0x7fffu + ((v.u >> 16) & 1u);   // RNE
    return (unsigned short)(r >> 16);
}

// async global->LDS, 16B per lane, LDS dest = wave-uniform base + lane*16
__device__ __forceinline__ void gl2lds16(const void* g, void* l) {
    __builtin_amdgcn_global_load_lds(
        (const __attribute__((address_space(1))) void*)g,
        (__attribute__((address_space(3))) void*)l, 16, 0, 0);
}

// ---------------- cast hidden_states f32 -> bf16 ----------------
__global__ void k_cast_hs(const float* __restrict__ in, unsigned short* __restrict__ out, int n8) {
    int i = blockIdx.x * blockDim.x + threadIdx.x;
    if (i >= n8) return;
    const float4* p = (const float4*)in + (size_t)i * 2;
    float4 a = p[0], b = p[1];
    u16x8 o;
    o[0]=f2bf(a.x); o[1]=f2bf(a.y); o[2]=f2bf(a.z); o[3]=f2bf(a.w);
    o[4]=f2bf(b.x); o[5]=f2bf(b.y); o[6]=f2bf(b.z); o[7]=f2bf(b.w);
    ((u16x8*)out)[i] = o;
}

// ---------------- W (k,n) f32 -> Wt (n,k) bf16 ----------------
__global__ void k_wt(const float* __restrict__ Wq, const float* __restrict__ Wk,
                     const float* __restrict__ Wv, unsigned short* __restrict__ wt) {
    const float* W = blockIdx.z == 0 ? Wq : (blockIdx.z == 1 ? Wk : Wv);
    unsigned short* out = wt + (size_t)blockIdx.z * HDIM * HDIM;
    __shared__ float tile[64][65];
    int t = threadIdx.x;
    int k0 = blockIdx.x * 64, n0 = blockIdx.y * 64;
    int r = t >> 2, c4 = t & 3;
#pragma unroll
    for (int j = 0; j < 16; j += 4) {
        float4 v = *(const float4*)&W[(size_t)(k0 + r) * HDIM + n0 + c4 * 16 + j];
        tile[r][c4*16+j+0] = v.x; tile[r][c4*16+j+1] = v.y;
        tile[r][c4*16+j+2] = v.z; tile[r][c4*16+j+3] = v.w;
    }
    __syncthreads();
    u16x8 o0, o1;
#pragma unroll
    for (int j = 0; j < 8; ++j) o0[j] = f2bf(tile[c4*16 + j][r]);
#pragma unroll
    for (int j = 0; j < 8; ++j) o1[j] = f2bf(tile[c4*16 + 8 + j][r]);
    *(u16x8*)&out[(size_t)(n0 + r) * HDIM + k0 + c4*16]     = o0;
    *(u16x8*)&out[(size_t)(n0 + r) * HDIM + k0 + c4*16 + 8] = o1;
}

// ---------------- projection GEMM (m97 structure, template-specialized) ----------------
// 128x128 tile, BK=64, global_load_lds staging (source-side XOR swizzle,
// linear LDS dest), 32KB LDS, 2 barriers/K-tile. TR=false: out (bh,s,d)
// for Q/K (blockIdx.z selects). TR=true: operands swapped in MFMA -> acc
// rows = n(d); writes V^T (bh,d,s) directly. Compile-time TR keeps each
// instantiation's regalloc tight (runtime-z fusion cost 2x: 132 VGPR, r9).
template<bool TR>
__global__ __launch_bounds__(256) void k_proj(const unsigned short* __restrict__ hsb,
                                              const unsigned short* __restrict__ wtb,
                                              unsigned short* __restrict__ outbuf) {
    __shared__ __align__(16) unsigned short As[8192];   // [128 rows][128B], swizzled slots
    __shared__ __align__(16) unsigned short Bs[8192];
    const char* Abase = (const char*)hsb;
    const char* Bbase = (const char*)(wtb + (size_t)blockIdx.z * HDIM * HDIM);
    unsigned short* out = outbuf + (size_t)blockIdx.z * (2u * NHD * SLEN * DH);
    int m0 = blockIdx.x * 128, n0 = blockIdx.y * 128;
    int t = threadIdx.x;
    int w = t >> 6, l = t & 63, g = l >> 4, c = l & 15;
    int wm = w >> 1, wn = w & 1;
    int lr = l >> 3, ls = l & 7, sw = ls ^ lr;          // stage swizzle (slot ^= row&7)
    int c7 = c & 7;
    f32x4 acc[4][4];
#pragma unroll
    for (int i = 0; i < 4; ++i)
#pragma unroll
        for (int j = 0; j < 4; ++j) acc[i][j] = (f32x4){0.f,0.f,0.f,0.f};

    for (int kt = 0; kt < HDIM; kt += 64) {
        __syncthreads();
#pragma unroll
        for (int i = 0; i < 4; ++i) {
            int rowb = w * 32 + i * 8;                   // 8 rows per issue
            gl2lds16(Abase + (size_t)(m0 + rowb + lr) * 1536 + kt * 2 + sw * 16,
                     (char*)As + rowb * 128);
            gl2lds16(Bbase + (size_t)(n0 + rowb + lr) * 1536 + kt * 2 + sw * 16,
                     (char*)Bs + rowb * 128);
        }
        __syncthreads();                                 // drains vmcnt before reads
#pragma unroll
        for (int ks = 0; ks < 2; ++ks) {
            bf16x8 af[4], bf_[4];
#pragma unroll
            for (int mt = 0; mt < 4; ++mt)
                af[mt]  = *(const bf16x8*)((const char*)As
                            + (64*wm + 16*mt + c) * 128 + (((ks*4 + g) ^ c7) * 16));
#pragma unroll
            for (int nt = 0; nt < 4; ++nt)
                bf_[nt] = *(const bf16x8*)((const char*)Bs
                            + (64*wn + 16*nt + c) * 128 + (((ks*4 + g) ^ c7) * 16));
#pragma unroll
            for (int i = 0; i < 4; ++i)
#pragma unroll
                for (int j = 0; j < 4; ++j)
                    acc[i][j] = TR
                        ? __builtin_amdgcn_mfma_f32_16x16x32_bf16(bf_[i], af[j], acc[i][j], 0, 0, 0)
                        : __builtin_amdgcn_mfma_f32_16x16x32_bf16(af[i], bf_[j], acc[i][j], 0, 0, 0);
        }
    }
#pragma unroll
    for (int i = 0; i < 4; ++i)
#pragma unroll
        for (int j = 0; j < 4; ++j)
#pragma unroll
            for (int r2 = 0; r2 < 4; ++r2) {
                if (!TR) {
                    int m = m0 + 64*wm + 16*i + 4*g + r2;     // s-dim (acc row)
                    int n = n0 + 64*wn + 16*j + c;            // h*64+d (acc col)
                    int bb = m >> 12, s = m & 4095;
                    int hh = n >> 6,  d = n & 63;
                    out[(((size_t)bb * NHD + hh) * SLEN + s) * DH + d] = f2bf(acc[i][j][r2]);
                } else {
                    int n = n0 + 64*wn + 16*i + 4*g + r2;     // h*64+d (acc row)
                    int m = m0 + 64*wm + 16*j + c;            // s-dim (acc col)
                    int bb = m >> 12, s = m & 4095;
                    int hh = n >> 6,  d = n & 63;
                    out[(((size_t)bb * NHD + hh) * DH + d) * SLEN + s] = f2bf(acc[i][j][r2]);
                }
            }
}

// ---------------- flash-style block-sparse attention (v8) ----------------
// K double-buffered (first reader each step), V single-buffered (last
// reader; staged right after the post-PV barrier, lands during next
// QK+softmax). LDS 32KB. All sync via __syncthreads (vmcnt-drain + fence
// semantics) -- proven correct r9/r10.
__global__ __launch_bounds__(256) void k_attn(
    const unsigned short* __restrict__ Qb, const unsigned short* __restrict__ Kb,
    const unsigned short* __restrict__ VTb,
    const int* __restrict__ rand_attn,
    const float* __restrict__ band_mask, const float* __restrict__ from_mask,
    const float* __restrict__ to_mask, const float* __restrict__ fbm,
    const float* __restrict__ tbm,
    float* __restrict__ out, float* __restrict__ partials)
{
    __shared__ __align__(16) unsigned short Kt[2][4096];   // dbuf K: 16KB
    __shared__ __align__(16) unsigned short Vt[4096];      // single V: 8KB
    __shared__ __align__(16) char plds[4 * 2048];          // per-wave P: 8KB

    const float SC = 0.125f * LOG2E;          // qk scale in log2 domain
    const float PL = PEN * LOG2E;             // penalty in log2 domain
    const float THR2 = 8.0f * LOG2E;          // defer-max threshold (log2)

    int i0 = blockIdx.x;
    int gid = (i0 & 7) * 234 + (i0 >> 3);           // XCD swizzle (1872 = 8*234)
    int bh = gid / 78, task = gid - bh * 78;
    int b = bh / NHD, h = bh - b * NHD;
    int t = threadIdx.x;
    int wq = t >> 6, l = t & 63, g = l >> 4, c = l & 15;
    int lr = l >> 3, ls = l & 7, sw = ls ^ lr;      // stage swizzle
    int c7 = c & 7;

    // ---- task -> 8 step descriptors (kv: 0=to_mask 1=band 2=rand 3=skip) ----
    int row, mode = 0, pslot = 0;
    int blkj[8], kvj[8], sbj[8];
#pragma unroll
    for (int j = 0; j < 8; ++j) sbj[j] = 0;
    if (task < 8) {
        row = 0; mode = 1; pslot = task;
#pragma unroll
        for (int j = 0; j < 8; ++j) { blkj[j] = task * 8 + j; kvj[j] = 0; }
    } else if (task >= 70) {
        row = 63; mode = 1; pslot = task - 70;
#pragma unroll
        for (int j = 0; j < 8; ++j) { blkj[j] = pslot * 8 + j; kvj[j] = 0; }
    } else {
        row = task - 7;                              // 1..62
        int rbase = ((b * NHD + h) * 62 + (row - 1)) * 3;
        blkj[4] = rand_attn[rbase];
        blkj[5] = rand_attn[rbase + 1];
        blkj[6] = rand_attn[rbase + 2];
        kvj[4] = kvj[5] = kvj[6] = 2;
        blkj[0] = 0; kvj[0] = 0;
        if (row == 1) {
            blkj[1]=1;  blkj[2]=2;  blkj[3]=63; kvj[1]=kvj[2]=kvj[3]=0;
            blkj[7]=0;  kvj[7]=3;
        } else if (row == 62) {
            blkj[1]=61; blkj[2]=62; blkj[3]=63; kvj[1]=kvj[2]=kvj[3]=0;
            blkj[7]=0;  kvj[7]=3;
        } else {
            blkj[1]=row-1; blkj[2]=row; blkj[3]=row+1;
            kvj[1]=kvj[2]=kvj[3]=1; sbj[1]=0; sbj[2]=64; sbj[3]=128;
            blkj[7]=63; kvj[7]=0;
        }
    }

    size_t bhoff = (size_t)bh * SLEN * DH;
    const char* Kbase = (const char*)(Kb + bhoff);                  // [key][128B]
    const char* Vbase = (const char*)(VTb + (size_t)bh * DH * SLEN); // [d][8192B]
    int q0 = row * 64 + wq * 16;

    // Q fragments (held in registers whole kernel)
    bf16x8 qf[2];
#pragma unroll
    for (int kk = 0; kk < 2; ++kk)
        qf[kk] = *(const bf16x8*)&Qb[bhoff + (size_t)(q0 + c) * DH + kk * 32 + 8 * g];

    float fmq = fbm[(b * NBLK + row) * 64 + wq * 16 + c];
    size_t bm_base = ((size_t)(b * 60 + row - 2) * 64 + (wq * 16 + c)) * 192;
    int tm_base = b * SLEN;

    float m_run = -1e30f, l_run = 0.f;
    f32x4 o_acc[4];
#pragma unroll
    for (int dt = 0; dt < 4; ++dt) o_acc[dt] = (f32x4){0.f,0.f,0.f,0.f};

    char* myl = plds + wq * 2048 + c * 128;
    int swz = c7 << 4;

    auto stageK = [&](int blk, int nb) __attribute__((always_inline)) {
#pragma unroll
        for (int ii = 0; ii < 2; ++ii) {
            int i = wq * 2 + ii;                          // chunk 0..7 (8 rows each)
            gl2lds16(Kbase + (size_t)blk * 8192 + (size_t)(i*8 + lr) * 128 + sw * 16,
                     (char*)&Kt[nb][0] + i * 1024);
        }
    };
    auto stageV = [&](int blk) __attribute__((always_inline)) {
#pragma unroll
        for (int ii = 0; ii < 2; ++ii) {
            int i = wq * 2 + ii;
            gl2lds16(Vbase + (size_t)(i*8 + lr) * 8192 + (size_t)blk * 128 + sw * 16,
                     (char*)Vt + i * 1024);
        }
    };

    // ---- mask -> precomputed penalty (log2 domain), overlapped ahead ----
    auto loadpen = [&](int kv, int blk, int sb, float4* pen) __attribute__((always_inline)) {
        if (kv == 0) {
#pragma unroll
            for (int mt = 0; mt < 4; ++mt) {
                float4 mk = *(const float4*)&to_mask[tm_base + blk * 64 + mt * 16 + 4 * g];
                pen[mt].x = (1.f - mk.x) * PL; pen[mt].y = (1.f - mk.y) * PL;
                pen[mt].z = (1.f - mk.z) * PL; pen[mt].w = (1.f - mk.w) * PL;
            }
        } else if (kv == 1) {
#pragma unroll
            for (int mt = 0; mt < 4; ++mt) {
                float4 mk = *(const float4*)&band_mask[bm_base + sb + mt * 16 + 4 * g];
                pen[mt].x = (1.f - mk.x) * PL; pen[mt].y = (1.f - mk.y) * PL;
                pen[mt].z = (1.f - mk.z) * PL; pen[mt].w = (1.f - mk.w) * PL;
            }
        } else if (kv == 2) {
#pragma unroll
            for (int mt = 0; mt < 4; ++mt) {
                float4 tb = *(const float4*)&tbm[(size_t)(b * NBLK + blk) * 64 + mt * 16 + 4 * g];
                pen[mt].x = (1.f - fmq * tb.x) * PL; pen[mt].y = (1.f - fmq * tb.y) * PL;
                pen[mt].z = (1.f - fmq * tb.z) * PL; pen[mt].w = (1.f - fmq * tb.w) * PL;
            }
        }
    };

    // ---- phase 1: QK^T + softmax + pack P (reads Kt[nb]) ----
    auto qk_sm = [&](int nb, const float4* pen) __attribute__((always_inline)) {
        bf16x8 kf[4][2];
#pragma unroll
        for (int mt = 0; mt < 4; ++mt)
#pragma unroll
            for (int kk = 0; kk < 2; ++kk)
                kf[mt][kk] = *(const bf16x8*)((const char*)&Kt[nb][0]
                              + (mt*16 + c) * 128 + (((kk*4 + g) ^ c7) * 16));
        f32x4 sa[4];
#pragma unroll
        for (int mt = 0; mt < 4; ++mt) sa[mt] = (f32x4){0.f,0.f,0.f,0.f};
#pragma unroll
        for (int kk = 0; kk < 2; ++kk)
#pragma unroll
            for (int mt = 0; mt < 4; ++mt)
                sa[mt] = __builtin_amdgcn_mfma_f32_16x16x32_bf16(kf[mt][kk], qf[kk], sa[mt], 0, 0, 0);
#pragma unroll
        for (int mt = 0; mt < 4; ++mt) {
            sa[mt][0] = sa[mt][0] * SC + pen[mt].x;
            sa[mt][1] = sa[mt][1] * SC + pen[mt].y;
            sa[mt][2] = sa[mt][2] * SC + pen[mt].z;
            sa[mt][3] = sa[mt][3] * SC + pen[mt].w;
        }
        float pm = -1e30f;
#pragma unroll
        for (int mt = 0; mt < 4; ++mt)
#pragma unroll
            for (int r2 = 0; r2 < 4; ++r2) pm = fmaxf(pm, sa[mt][r2]);
        pm = fmaxf(pm, __shfl_xor(pm, 16));
        pm = fmaxf(pm, __shfl_xor(pm, 32));
        if (__ballot(pm > m_run + THR2)) {
            bool need = pm > m_run + THR2;
            float mnew = need ? pm : m_run;
            float scale = exp2f(m_run - mnew);
            m_run = mnew;
            l_run *= scale;
#pragma unroll
            for (int dt = 0; dt < 4; ++dt)
#pragma unroll
                for (int r2 = 0; r2 < 4; ++r2) o_acc[dt][r2] *= scale;
        }
        float rs = 0.f;
#pragma unroll
        for (int mt = 0; mt < 4; ++mt)
#pragma unroll
            for (int r2 = 0; r2 < 4; ++r2) {
                float e = exp2f(sa[mt][r2] - m_run);
                sa[mt][r2] = e;
                rs += e;
            }
        rs += __shfl_xor(rs, 16);
        rs += __shfl_xor(rs, 32);
        l_run += rs;
#pragma unroll
        for (int mt = 0; mt < 4; ++mt) {
            union { __bf16 hh[4]; unsigned long long u; } pk_;
            pk_.hh[0] = (__bf16)sa[mt][0]; pk_.hh[1] = (__bf16)sa[mt][1];
            pk_.hh[2] = (__bf16)sa[mt][2]; pk_.hh[3] = (__bf16)sa[mt][3];
            *(unsigned long long*)(myl + ((mt * 32 + g * 8) ^ swz)) = pk_.u;
        }
        asm volatile("" ::: "memory");
    };

    // ---- phase 2: PV (reads Vt + own P) ----
    auto pv = [&]() __attribute__((always_inline)) {
        bf16x8 pf0 = *(const bf16x8*)(myl + ((g * 16) ^ swz));
        bf16x8 pf1 = *(const bf16x8*)(myl + ((64 + g * 16) ^ swz));
#pragma unroll
        for (int dt = 0; dt < 4; ++dt) {
            bf16x8 v0 = *(const bf16x8*)((const char*)Vt
                          + (dt*16 + c) * 128 + ((g ^ c7) * 16));
            bf16x8 v1 = *(const bf16x8*)((const char*)Vt
                          + (dt*16 + c) * 128 + (((4 + g) ^ c7) * 16));
            o_acc[dt] = __builtin_amdgcn_mfma_f32_16x16x32_bf16(v0, pf0, o_acc[dt], 0, 0, 0);
            o_acc[dt] = __builtin_amdgcn_mfma_f32_16x16x32_bf16(v1, pf1, o_acc[dt], 0, 0, 0);
        }
    };

    // ---- pipelined 8-step loop: K dbuf staged 1 ahead; V single-buffered ----
    float4 penA[4], penB[4];
    stageK(blkj[0], 0);
    stageV(blkj[0]);
    loadpen(kvj[0], blkj[0], sbj[0], penA);
    __syncthreads();                                  // drains K0,V0
#pragma unroll
    for (int tt = 0; tt < 8; ++tt) {
        int nb = tt & 1;
        if (tt < 7) {
            stageK(blkj[tt + 1], nb ^ 1);             // K(t+1): buffer free since t-1
            loadpen(kvj[tt + 1], blkj[tt + 1], sbj[tt + 1], nb ? penA : penB);
        }
        bool active = (kvj[tt] != 3);                 // block-uniform
        if (active) qk_sm(nb, nb ? penB : penA);
        __syncthreads();                              // drains V(t) (+K(t+1)); all past Kt reads
        if (active) pv();
        __syncthreads();                              // all waves done reading Vt
        if (tt < 7) stageV(blkj[tt + 1]);             // lands during next QK+softmax
    }

    if (mode == 0) {
        int s = q0 + c;
        float fm = from_mask[b * SLEN + s];
        float inv = fm / l_run;
        size_t obase = ((size_t)b * SLEN + s) * HDIM + h * DH;
#pragma unroll
        for (int dt = 0; dt < 4; ++dt) {
            float4 val;
            val.x = o_acc[dt][0] * inv;
            val.y = o_acc[dt][1] * inv;
            val.z = o_acc[dt][2] * inv;
            val.w = o_acc[dt][3] * inv;
            *(float4*)&out[obase + dt * 16 + 4 * g] = val;
        }
    } else {
        float* pb = partials + (size_t)((bh * 2 + (row == 63 ? 1 : 0)) * 8 + pslot) * 4224;
        int q = wq * 16 + c;
#pragma unroll
        for (int dt = 0; dt < 4; ++dt) {
            float4 val;
            val.x = o_acc[dt][0]; val.y = o_acc[dt][1];
            val.z = o_acc[dt][2]; val.w = o_acc[dt][3];
            *(float4*)&pb[q * 64 + dt * 16 + 4 * g] = val;
        }
        if (g == 0) {
            pb[4096 + q] = m_run;                     // log2 domain
            pb[4160 + q] = l_run;
        }
    }
}

// ---------------- combine 8 partials for row-blocks 0 and 63 ----------------
// partial o_i is raw (unnormalized); m_i in log2 domain -> weight exp2(m_i-M).
__global__ void k_combine(const float* __restrict__ partials, const float* __restrict__ from_mask,
                          float* __restrict__ out) {
    int gid = blockIdx.x;          // 48 = bh*2 + rb
    int bh = gid >> 1, rb = gid & 1;
    int b = bh / NHD, h = bh - b * NHD;
    int t = threadIdx.x;           // 256
    int q = t >> 2, dc = (t & 3) * 16;
    const float* base = partials + (size_t)gid * 8 * 4224;
    float M = -1e30f;
#pragma unroll
    for (int i = 0; i < 8; ++i) M = fmaxf(M, base[i*4224 + 4096 + q]);
    float L = 0.f, cx[16];
#pragma unroll
    for (int j = 0; j < 16; ++j) cx[j] = 0.f;
    for (int i = 0; i < 8; ++i) {
        float w = exp2f(base[i*4224 + 4096 + q] - M);
        L += base[i*4224 + 4160 + q] * w;
#pragma unroll
        for (int j = 0; j < 16; ++j) cx[j] += base[i*4224 + q*64 + dc + j] * w;
    }
    int s = (rb ? 4032 : 0) + q;
    float fm = from_mask[b * SLEN + s];
    float inv = fm / L;
#pragma unroll
    for (int j = 0; j < 16; ++j)
        out[((size_t)b * SLEN + s) * HDIM + h * DH + dc + j] = cx[j] * inv;
}

extern "C" void kernel_launch(void* const* d_in, const int* in_sizes, int n_in,
                              void* d_out, int out_size, void* d_ws, size_t ws_size,
                              hipStream_t stream) {
    const float* hs    = (const float*)d_in[0];
    const float* Wq    = (const float*)d_in[1];
    const float* Wk    = (const float*)d_in[2];
    const float* Wv    = (const float*)d_in[3];
    const float* band  = (const float*)d_in[4];
    const float* fromm = (const float*)d_in[5];
    const float* tom   = (const float*)d_in[6];
    const float* fbm   = (const float*)d_in[7];
    const float* tbm   = (const float*)d_in[8];
    const int*   ra    = (const int*)d_in[9];      // harness passes integers as int32
    float* out = (float*)d_out;

    // workspace layout (bytes):
    //  [0, 12.58M)  hsb  (bf16 hidden)
    //  [12.58M, 16.12M) wtb (3x768x768 bf16)
    //  [16.12M, 53.87M) qkv: z=0 Q (bh,s,d), z=1 K (bh,s,d), z=2 V^T (bh,d,s)
    //  [53.87M, 60.36M) partials (48 x 8 x 4224 f32)
    char* ws = (char*)d_ws;
    unsigned short* hsb = (unsigned short*)(ws);
    unsigned short* wtb = (unsigned short*)(ws + 12582912);
    unsigned short* qkv = (unsigned short*)(ws + 16121856);
    float* partials     = (float*)(ws + 53870592);

    k_cast_hs<<<3072, 256, 0, stream>>>(hs, hsb, 786432);
    k_wt<<<dim3(12, 12, 3), 256, 0, stream>>>(Wq, Wk, Wv, wtb);
    k_proj<false><<<dim3(64, 6, 2), 256, 0, stream>>>(hsb, wtb, qkv);
    k_proj<true><<<dim3(64, 6, 1), 256, 0, stream>>>(hsb, wtb + 2 * HDIM * HDIM,
                                                     qkv + 2 * 6291456);
    k_attn<<<1872, 256, 0, stream>>>(qkv, qkv + 6291456, qkv + 2 * 6291456, ra,
                                     band, fromm, tom, fbm, tbm, out, partials);
    k_combine<<<48, 256, 0, stream>>>(partials, fromm, out);
}